// Round 2
// baseline (852.997 us; speedup 1.0000x reference)
//
#include <hip/hip_runtime.h>

#define EPSF 1e-8f
#define LN2F 0.69314718055994530942f

// One WAVE per batch row b (B=8192): grid = B/4 blocks x 256 threads (4 rows/block).
// Row layout: p[b] = [E=8][C=1000] fp32. Output row = 8029 floats.
//
// Lane l owns classes {l, l+64, ..., l+960} (l<40 gets the 16th strip): every
// global load and raw-copy store is lane-contiguous (64 consecutive dwords).
// All cross-lane reduction is a single 6-step XOR butterfly per row — no LDS,
// no __syncthreads, no cross-wave merge. (mx1, argmax) reduce via a packed
// u64 key (float bits << 32 | ~class): p>0 so float bits are monotonic, and
// ties pick the smallest class index, matching jnp.argmax semantics.
//
// NOTE: stores are PLAIN (cached). Nontemporal stores caused 4.4x HBM write
// amplification (273 MB -> 1.2 GB, rocprof round 1): the 8029-float row
// stride misaligns every 256 B wave-store against 128 B lines, and without
// L2 write-combining the partial lines never merge with the adjacent strip.
__global__ __launch_bounds__(256, 6) void gating_feat_kernel(
    const float* __restrict__ pin, float* __restrict__ out, int B)
{
    const int lane = threadIdx.x & 63;
    const int b = blockIdx.x * 4 + (threadIdx.x >> 6);
    if (b >= B) return;
    const float* __restrict__ rin  = pin + (size_t)b * 8000;
    float*       __restrict__ rout = out + (size_t)b * 8029;

    // accumulators (log2 space; single ln2 fold at the epilogue)
    float plogp[8], mx1[8], mx2[8];
    int   am[8];
#pragma unroll
    for (int e = 0; e < 8; ++e) {
        plogp[e] = 0.f; mx1[e] = 0.f; mx2[e] = 0.f; am[e] = 0x7fffffff;
    }
    float cross = 0.f;   // sum_c sum_{i<j} p_i * log2(p_j+eps)   (prefix trick)
    float mixent = 0.f;  // sum_c m * log2(m+eps)
    float varacc = 0.f;  // sum_c (sum_e p^2 - 8 m^2)

#pragma unroll
    for (int s = 0; s < 16; ++s) {
        const int c = lane + (s << 6);
        if (s < 15 || lane < 40) {          // c < 1000; only s==15 diverges
            float pr[8];
#pragma unroll
            for (int e = 0; e < 8; ++e)
                pr[e] = rin[e * 1000 + c];
            // raw copy to out (plain cached stores -> L2 write-combining)
#pragma unroll
            for (int e = 0; e < 8; ++e)
                rout[e * 1000 + c] = pr[e];

            float prefix = 0.f, ss = 0.f;
#pragma unroll
            for (int e = 0; e < 8; ++e) {
                const float pv = pr[e];
                const float lp = __log2f(pv + EPSF);          // v_log_f32 only
                plogp[e] = __fmaf_rn(pv, lp, plogp[e]);
                // branchless top-2 + argmax (strict '>' keeps first/lowest c)
                const bool gt = pv > mx1[e];
                mx2[e] = fmaxf(mx2[e], fminf(pv, mx1[e]));
                if (gt) { mx1[e] = pv; am[e] = c; }           // 2x cndmask
                cross  = __fmaf_rn(prefix, lp, cross);
                prefix += pv;
                ss     = __fmaf_rn(pv, pv, ss);
            }
            const float m = prefix * 0.125f;
            mixent = __fmaf_rn(m, __log2f(m + EPSF), mixent);
            varacc += ss - 8.f * m * m;
        }
    }

    // pack (value, argmax) so the max-reduce is tie-correct and branchless
    unsigned long long key[8];
#pragma unroll
    for (int e = 0; e < 8; ++e)
        key[e] = ((unsigned long long)__float_as_uint(mx1[e]) << 32)
               | (unsigned)(0xFFFFFFFFu - (unsigned)am[e]);

    // single 6-step XOR butterfly: every lane ends with the row totals
#pragma unroll
    for (int off = 32; off >= 1; off >>= 1) {
#pragma unroll
        for (int e = 0; e < 8; ++e) {
            const unsigned long long ok = __shfl_xor(key[e], off);
            const float o2 = __shfl_xor(mx2[e], off);
            const float a1 = __uint_as_float((unsigned)(key[e] >> 32));
            const float b1 = __uint_as_float((unsigned)(ok >> 32));
            // merged 2nd-max of two (top1, top2) pairs
            mx2[e] = fmaxf(fmaxf(mx2[e], o2), fminf(a1, b1));
            if (ok > key[e]) key[e] = ok;
            plogp[e] += __shfl_xor(plogp[e], off);
        }
        cross  += __shfl_xor(cross,  off);
        mixent += __shfl_xor(mixent, off);
        varacc += __shfl_xor(varacc, off);
    }

    if (lane == 0) {
        float sum_plogp = 0.f, wsum = 0.f;
        int amf[8];
#pragma unroll
        for (int e = 0; e < 8; ++e) {
            const float pe = plogp[e] * LN2F;                 // back to nats
            sum_plogp += pe;
            wsum += (float)(7 - e) * pe;                      // sum_{i<j} plogp_i
            const float m1 = __uint_as_float((unsigned)(key[e] >> 32));
            amf[e] = (int)(0xFFFFFFFFu - (unsigned)(key[e] & 0xFFFFFFFFu));
            rout[8000 + e] = -pe;                             // expert_entropy
            rout[8008 + e] = m1;                              // expert_confidence
            rout[8016 + e] = m1 - mx2[e];                     // expert_margin
        }
        int nu = 0;
#pragma unroll
        for (int i = 0; i < 8; ++i) {
            bool u = true;
#pragma unroll
            for (int j = 0; j < i; ++j) u = u && (amf[j] != amf[i]);
            nu += u ? 1 : 0;
        }
        rout[8024] = (float)(nu - 1) * (1.f / 7.f);           // disagreement
        rout[8025] = (wsum - cross * LN2F) * (1.f / 28.f);    // mean_pairwise_kl
        const float me = -mixent * LN2F;
        rout[8026] = me;                                      // mixture_entropy
        rout[8027] = varacc * (1.f / 7000.f);                 // post_var
        rout[8028] = me + sum_plogp * 0.125f;                 // mutual_info
    }
}

extern "C" void kernel_launch(void* const* d_in, const int* in_sizes, int n_in,
                              void* d_out, int out_size, void* d_ws, size_t ws_size,
                              hipStream_t stream) {
    const float* p = (const float*)d_in[0];
    float* out = (float*)d_out;
    const int B = in_sizes[0] / 8000;   // 8192
    gating_feat_kernel<<<(B + 3) / 4, 256, 0, stream>>>(p, out, B);
}

// Round 3
// 810.798 us; speedup vs baseline: 1.0520x; 1.0520x over previous
//
#include <hip/hip_runtime.h>

#define EPSF 1e-8f
#define LN2F 0.69314718055994530942f

// One WAVE per batch row b (B=8192): grid = B/4 blocks x 256 threads.
// Row layout: p[b] = [E=8][C=1000] fp32. Output row = 8029 floats.
//
// Phase 1 (stats): lane l owns classes {l, l+64, ...}; loads only, no stores.
//   Single 6-step XOR butterfly per row; no LDS, no __syncthreads.
// Phase 2 (copy): the 8000-float raw copy is done as a LINE-ALIGNED memcpy
//   with a per-row shift: every body store is a 256B-aligned, fully-covered
//   256 B sector. Round 1/2 rocprof showed 4.4x HBM write amplification
//   (1.18 GB vs 264 MB) because misaligned 256 B strip-stores left partial
//   lines that evicted between iterations (~35 us apart) -> RFO + re-evict.
//   Aligned full-sector stores eliminate partial-line thrash entirely; the
//   copy's re-read of the input is L2/L3-served (input ~ L3 capacity).
__global__ __launch_bounds__(256, 6) void gating_feat_kernel(
    const float* __restrict__ pin, float* __restrict__ out, int B)
{
    const int lane = threadIdx.x & 63;
    const int b = blockIdx.x * 4 + (threadIdx.x >> 6);
    if (b >= B) return;
    const float* __restrict__ rin  = pin + (size_t)b * 8000;
    float*       __restrict__ rout = out + (size_t)b * 8029;

    // ---- phase 1: stats accumulation (log2 space; ln2 fold at epilogue) ----
    float plogp[8], mx1[8], mx2[8];
    int   am[8];
#pragma unroll
    for (int e = 0; e < 8; ++e) {
        plogp[e] = 0.f; mx1[e] = 0.f; mx2[e] = 0.f; am[e] = 0x7fffffff;
    }
    float cross = 0.f;   // sum_c sum_{i<j} p_i * log2(p_j+eps)   (prefix trick)
    float mixent = 0.f;  // sum_c m * log2(m+eps)
    float varacc = 0.f;  // sum_c (sum_e p^2 - 8 m^2)

#pragma unroll
    for (int s = 0; s < 16; ++s) {
        const int c = lane + (s << 6);
        if (s < 15 || lane < 40) {          // c < 1000; only s==15 diverges
            float pr[8];
#pragma unroll
            for (int e = 0; e < 8; ++e)
                pr[e] = rin[e * 1000 + c];

            float prefix = 0.f, ss = 0.f;
#pragma unroll
            for (int e = 0; e < 8; ++e) {
                const float pv = pr[e];
                const float lp = __log2f(pv + EPSF);          // v_log_f32 only
                plogp[e] = __fmaf_rn(pv, lp, plogp[e]);
                // branchless top-2 + argmax (strict '>' keeps first/lowest c)
                const bool gt = pv > mx1[e];
                mx2[e] = fmaxf(mx2[e], fminf(pv, mx1[e]));
                if (gt) { mx1[e] = pv; am[e] = c; }           // 2x cndmask
                cross  = __fmaf_rn(prefix, lp, cross);
                prefix += pv;
                ss     = __fmaf_rn(pv, pv, ss);
            }
            const float m = prefix * 0.125f;
            mixent = __fmaf_rn(m, __log2f(m + EPSF), mixent);
            varacc += ss - 8.f * m * m;
        }
    }

    // pack (value, argmax) so the max-reduce is tie-correct and branchless
    unsigned long long key[8];
#pragma unroll
    for (int e = 0; e < 8; ++e)
        key[e] = ((unsigned long long)__float_as_uint(mx1[e]) << 32)
               | (unsigned)(0xFFFFFFFFu - (unsigned)am[e]);

    // single 6-step XOR butterfly: every lane ends with the row totals
#pragma unroll
    for (int off = 32; off >= 1; off >>= 1) {
#pragma unroll
        for (int e = 0; e < 8; ++e) {
            const unsigned long long ok = __shfl_xor(key[e], off);
            const float o2 = __shfl_xor(mx2[e], off);
            const float a1 = __uint_as_float((unsigned)(key[e] >> 32));
            const float b1 = __uint_as_float((unsigned)(ok >> 32));
            mx2[e] = fmaxf(fmaxf(mx2[e], o2), fminf(a1, b1));
            if (ok > key[e]) key[e] = ok;
            plogp[e] += __shfl_xor(plogp[e], off);
        }
        cross  += __shfl_xor(cross,  off);
        mixent += __shfl_xor(mixent, off);
        varacc += __shfl_xor(varacc, off);
    }

    // ---- phase 2: line-aligned raw copy of the 8000-float row ----
    // head: dwords until rout reaches a 256 B boundary; body: 256 B-aligned
    // fully-covered sectors (64 dwords/instr); tail: remainder.
    {
        const int align = (int)(((size_t)rout >> 2) & 63u);
        const int head  = (64 - align) & 63;
        if (lane < head) rout[lane] = rin[lane];
        const int nbody = (8000 - head) >> 6;              // 124 or 125
        const float* __restrict__ src = rin + head + lane;
        float* __restrict__ dst = rout + head + lane;
        int i = 0;
        for (; i + 8 <= nbody; i += 8) {                   // 8 outstanding loads
            float v[8];
#pragma unroll
            for (int k = 0; k < 8; ++k) v[k] = src[(i + k) << 6];
#pragma unroll
            for (int k = 0; k < 8; ++k) dst[(i + k) << 6] = v[k];
        }
        for (; i < nbody; ++i) dst[i << 6] = src[i << 6];
        const int done = head + (nbody << 6);
        if (lane < 8000 - done) rout[done + lane] = rin[done + lane];
    }

    // ---- epilogue: 29 stats (adjacent in time to the copy tail -> lines
    //      at rout+8000 merge in L2 with the tail stores) ----
    if (lane == 0) {
        float sum_plogp = 0.f, wsum = 0.f;
        int amf[8];
#pragma unroll
        for (int e = 0; e < 8; ++e) {
            const float pe = plogp[e] * LN2F;                 // back to nats
            sum_plogp += pe;
            wsum += (float)(7 - e) * pe;                      // sum_{i<j} plogp_i
            const float m1 = __uint_as_float((unsigned)(key[e] >> 32));
            amf[e] = (int)(0xFFFFFFFFu - (unsigned)(key[e] & 0xFFFFFFFFu));
            rout[8000 + e] = -pe;                             // expert_entropy
            rout[8008 + e] = m1;                              // expert_confidence
            rout[8016 + e] = m1 - mx2[e];                     // expert_margin
        }
        int nu = 0;
#pragma unroll
        for (int i = 0; i < 8; ++i) {
            bool u = true;
#pragma unroll
            for (int j = 0; j < i; ++j) u = u && (amf[j] != amf[i]);
            nu += u ? 1 : 0;
        }
        rout[8024] = (float)(nu - 1) * (1.f / 7.f);           // disagreement
        rout[8025] = (wsum - cross * LN2F) * (1.f / 28.f);    // mean_pairwise_kl
        const float me = -mixent * LN2F;
        rout[8026] = me;                                      // mixture_entropy
        rout[8027] = varacc * (1.f / 7000.f);                 // post_var
        rout[8028] = me + sum_plogp * 0.125f;                 // mutual_info
    }
}

extern "C" void kernel_launch(void* const* d_in, const int* in_sizes, int n_in,
                              void* d_out, int out_size, void* d_ws, size_t ws_size,
                              hipStream_t stream) {
    const float* p = (const float*)d_in[0];
    float* out = (float*)d_out;
    const int B = in_sizes[0] / 8000;   // 8192
    gating_feat_kernel<<<(B + 3) / 4, 256, 0, stream>>>(p, out, B);
}